// Round 1
// baseline (191.864 us; speedup 1.0000x reference)
//
#include <hip/hip_runtime.h>
#include <hip/hip_bf16.h>
#include <stdint.h>

#define BATCH 4096
#define TLEN  1024
#define MSTR  72     // LDS stride (bf16 elems) for T matrices; 144B keeps b64/b128 alignment
#define CSTR  68     // combine buffer stride (f32); 272B = 17*16 keeps f32x4 alignment

// ---- LDS layout (bytes) ----
#define OFF_T    0        // Tsm plain [64][MSTR] bf16   (bwd A source)
#define OFF_G    9216     // Tsm^T     [64][MSTR] bf16   (fwd A source)
#define OFF_PE   18432    // float pE[2][64]
#define OFF_PIV  18944    // float piv[64]
#define OFF_YB   19200    // u64 yball[16][17] (padded stride)
#define OFF_CMB  21376    // float gamma[16][CSTR]
#define OFF_LACB 25728    // float laccB[16]
#define SMEM_SZ  25792

typedef short bf16x4 __attribute__((ext_vector_type(4)));
typedef short bf16x8 __attribute__((ext_vector_type(8)));
typedef float f32x4  __attribute__((ext_vector_type(4)));

#define MFMA(a,b,c) __builtin_amdgcn_mfma_f32_16x16x32_bf16(a,b,c,0,0,0)

// ---------------------------------------------------------------------------
// 256 wgs x 128 thr (2 waves). wg = 16-batch block, BOTH directions:
//   wave0: forward  alpha-chain, A = T^T (permuted k-order)
//   wave1: backward gamma-chain (gamma_t = e_t ⊙ beta_t), A = T (permuted)
// Main loop is register-only: the MFMA D-fragment (states m*16+4g+r, col lr)
// is repacked DIRECTLY as the next step's B-fragment; the A-fragments are
// gathered once with the matching k-slot permutation
//   sigma(h,g,j) = 32h + 4g + (j&3) + 16*(j>>2)
// (valid because A and B fragments share the same (g,j)->k map, as the
// previous kernel's B0/B1 usage proves). No LDS, no barriers, no select
// tree in the 511-step chain. Renorm every 16 steps via in-wave shuffles.
// Combine log(abar_512 . gamma_512) in-wg; single kernel, no workspace.
// ---------------------------------------------------------------------------
__global__ __launch_bounds__(128, 1) void hmm_fb(
    const int* __restrict__ y, const float* __restrict__ Tmat,
    const float* __restrict__ Emat, const float* __restrict__ Pi,
    float* __restrict__ out)
{
    __shared__ __align__(16) unsigned char SM[SMEM_SZ];

    const int tid  = threadIdx.x;
    const int wv   = tid >> 6;          // 0 = fwd, 1 = bwd
    const int lane = tid & 63;
    const int lr   = lane & 15;         // batch col
    const int g    = lane >> 4;         // k-group
    const int R0   = blockIdx.x << 4;

    float* pE  = (float*)(SM + OFF_PE);
    float* piv = (float*)(SM + OFF_PIV);
    const f32x4 zero = {0.f, 0.f, 0.f, 0.f};

    // ---- phase 0: emission + pi softmax (wave0) ----
    if (tid < 64) {
        const float e0 = Emat[tid*2+0], e1 = Emat[tid*2+1];
        const float em = fmaxf(e0, e1);
        const float p0 = __expf(e0-em), p1 = __expf(e1-em);
        const float ez = 1.0f / (p0 + p1);
        pE[tid]      = p0 * ez;
        pE[64 + tid] = p1 * ez;
        float v = Pi[tid];
        float mx = v;
        #pragma unroll
        for (int d = 1; d < 64; d <<= 1) mx = fmaxf(mx, __shfl_xor(mx, d));
        const float e = __expf(v - mx);
        float z = e;
        #pragma unroll
        for (int d = 1; d < 64; d <<= 1) z += __shfl_xor(z, d);
        piv[tid] = e / z;
    }

    // ---- phase 1: row-softmax of T -> plain + transposed bf16 ----
    {
        const int r  = tid >> 1;          // 0..63
        const int hh = tid & 1;           // 32-col half
        float v[32];
        #pragma unroll
        for (int q = 0; q < 8; q++) {
            const float4 t4 = *(const float4*)(Tmat + r*64 + hh*32 + q*4);
            v[q*4+0]=t4.x; v[q*4+1]=t4.y; v[q*4+2]=t4.z; v[q*4+3]=t4.w;
        }
        float mx = v[0];
        #pragma unroll
        for (int k = 1; k < 32; k++) mx = fmaxf(mx, v[k]);
        mx = fmaxf(mx, __shfl_xor(mx, 1));
        float z = 0.f;
        #pragma unroll
        for (int k = 0; k < 32; k++) { v[k] = __expf(v[k]-mx); z += v[k]; }
        z += __shfl_xor(z, 1);
        const float inv = 1.0f / z;
        __hip_bfloat16* Tsm = (__hip_bfloat16*)(SM + OFF_T);
        __hip_bfloat16* Gt  = (__hip_bfloat16*)(SM + OFF_G);
        #pragma unroll
        for (int k = 0; k < 32; k++) {
            const int j = hh*32 + k;
            const __hip_bfloat16 hb = __float2bfloat16(v[k] * inv);
            Tsm[r*MSTR + j] = hb;     // Tsm[s][s']
            Gt[j*MSTR + r]  = hb;     // Gt[s'][s] = T[s][s']
        }
    }
    __syncthreads();

    // ---- phase 2: gather permuted A-fragments (register-resident) ----
    // A[m][h] element j (lane g): col sigma = 32h + 4g + (j&3) + 16*(j>>2)
    bf16x8 A00,A01,A10,A11,A20,A21,A30,A31;
    {
        const __hip_bfloat16* Abase =
            (const __hip_bfloat16*)(SM + (wv == 0 ? OFF_G : OFF_T));
        #define LDFRAG(dst, m, h) { \
            const __hip_bfloat16* p_ = Abase + ((m)*16+lr)*MSTR + 32*(h) + 4*g; \
            bf16x4 lo_ = *(const bf16x4*)(p_); \
            bf16x4 hi_ = *(const bf16x4*)(p_ + 16); \
            dst[0]=lo_[0]; dst[1]=lo_[1]; dst[2]=lo_[2]; dst[3]=lo_[3]; \
            dst[4]=hi_[0]; dst[5]=hi_[1]; dst[6]=hi_[2]; dst[7]=hi_[3]; \
        }
        LDFRAG(A00,0,0); LDFRAG(A01,0,1); LDFRAG(A10,1,0); LDFRAG(A11,1,1);
        LDFRAG(A20,2,0); LDFRAG(A21,2,1); LDFRAG(A30,3,0); LDFRAG(A31,3,1);
        #undef LDFRAG
    }

    // ---- phase 3: ballot-pack y into LDS words ----
    unsigned long long* yball = (unsigned long long*)(SM + OFF_YB);
    #pragma unroll
    for (int q = 0; q < 8; q++) {
        const int row = wv*8 + q;
        const int* yr = y + (size_t)(R0 + row) * TLEN;
        #pragma unroll
        for (int w = 0; w < 16; w++) {
            const unsigned long long bal = __ballot(yr[w*64 + lane] != 0);
            if (lane == 0) yball[row*17 + w] = bal;
        }
    }
    __syncthreads();

    // ---- phase 4: per-lane bit-stream registers + e/init registers ----
    // stream bit s: fwd -> y[s+1] (t=1..511); bwd -> y[1022-s] (t=1022..512)
    unsigned long long BS[8];
    int initbit;
    {
        unsigned long long raw[8];
        if (wv == 0) {
            #pragma unroll
            for (int w = 0; w < 8; w++) raw[w] = yball[lr*17 + w];
        } else {
            #pragma unroll
            for (int w = 0; w < 8; w++) raw[w] = __brevll(yball[lr*17 + (15-w)]);
        }
        initbit = (int)(raw[0] & 1ull);           // fwd: y[0]; bwd: y[1023]
        #pragma unroll
        for (int w = 0; w < 7; w++) BS[w] = (raw[w] >> 1) | (raw[w+1] << 63);
        BS[7] = raw[7] >> 1;
    }

    f32x4 e0_0 = *(const f32x4*)(pE +       0 + 4*g);
    f32x4 e0_1 = *(const f32x4*)(pE +      16 + 4*g);
    f32x4 e0_2 = *(const f32x4*)(pE +      32 + 4*g);
    f32x4 e0_3 = *(const f32x4*)(pE +      48 + 4*g);
    f32x4 e1_0 = *(const f32x4*)(pE + 64 +  0 + 4*g);
    f32x4 e1_1 = *(const f32x4*)(pE + 64 + 16 + 4*g);
    f32x4 e1_2 = *(const f32x4*)(pE + 64 + 32 + 4*g);
    f32x4 e1_3 = *(const f32x4*)(pE + 64 + 48 + 4*g);

    f32x4 d0, d1, d2, d3;
    if (wv == 0) {                        // alpha_0 = piv ⊙ e_{y0}
        const f32x4 p0 = *(const f32x4*)(piv +  0 + 4*g);
        const f32x4 p1 = *(const f32x4*)(piv + 16 + 4*g);
        const f32x4 p2 = *(const f32x4*)(piv + 32 + 4*g);
        const f32x4 p3 = *(const f32x4*)(piv + 48 + 4*g);
        d0 = p0 * (initbit ? e1_0 : e0_0);
        d1 = p1 * (initbit ? e1_1 : e0_1);
        d2 = p2 * (initbit ? e1_2 : e0_2);
        d3 = p3 * (initbit ? e1_3 : e0_3);
    } else {                              // gamma_1023 = e_{y1023}
        d0 = initbit ? e1_0 : e0_0;
        d1 = initbit ? e1_1 : e0_1;
        d2 = initbit ? e1_2 : e0_2;
        d3 = initbit ? e1_3 : e0_3;
    }

    // ---- main loop: 511 register-only steps ----
    f32x4 t0, t1, t2, t3;
    #define DO_MM() { \
        union { __hip_bfloat16 h[8]; bf16x8 v; } b1_, b2_; \
        b1_.h[0]=__float2bfloat16(d0.x); b1_.h[1]=__float2bfloat16(d0.y); \
        b1_.h[2]=__float2bfloat16(d0.z); b1_.h[3]=__float2bfloat16(d0.w); \
        b1_.h[4]=__float2bfloat16(d1.x); b1_.h[5]=__float2bfloat16(d1.y); \
        b1_.h[6]=__float2bfloat16(d1.z); b1_.h[7]=__float2bfloat16(d1.w); \
        b2_.h[0]=__float2bfloat16(d2.x); b2_.h[1]=__float2bfloat16(d2.y); \
        b2_.h[2]=__float2bfloat16(d2.z); b2_.h[3]=__float2bfloat16(d2.w); \
        b2_.h[4]=__float2bfloat16(d3.x); b2_.h[5]=__float2bfloat16(d3.y); \
        b2_.h[6]=__float2bfloat16(d3.z); b2_.h[7]=__float2bfloat16(d3.w); \
        t0 = MFMA(A00, b1_.v, zero); t1 = MFMA(A10, b1_.v, zero); \
        t2 = MFMA(A20, b1_.v, zero); t3 = MFMA(A30, b1_.v, zero); \
        t0 = MFMA(A01, b2_.v, t0);   t1 = MFMA(A11, b2_.v, t1); \
        t2 = MFMA(A21, b2_.v, t2);   t3 = MFMA(A31, b2_.v, t3); \
    }

    float lacc = 0.f;
    #pragma unroll
    for (int blk = 0; blk < 8; blk++) {
        unsigned long long cur = BS[blk];
        const int n = (blk == 7) ? 63 : 64;     // 7*64 + 63 = 511 steps
        for (int i = 0; i < n; i++) {
            DO_MM();
            if ((i & 15) == 15) {               // renorm every 16 steps
                float S = t0.x+t0.y+t0.z+t0.w + t1.x+t1.y+t1.z+t1.w
                        + t2.x+t2.y+t2.z+t2.w + t3.x+t3.y+t3.z+t3.w;
                S += __shfl_xor(S, 16);
                S += __shfl_xor(S, 32);
                lacc += __logf(S);
                const float rn = __builtin_amdgcn_rcpf(S);
                t0 *= rn; t1 *= rn; t2 *= rn; t3 *= rn;
            }
            const bool yb = (cur & 1ull) != 0;
            cur >>= 1;
            d0 = t0 * (yb ? e1_0 : e0_0);
            d1 = t1 * (yb ? e1_1 : e0_1);
            d2 = t2 * (yb ? e1_2 : e0_2);
            d3 = t3 * (yb ? e1_3 : e0_3);
        }
    }

    // ---- fwd: one bare matvec (no emission) -> abar_512 ----
    if (wv == 0) {
        DO_MM();
        d0 = t0; d1 = t1; d2 = t2; d3 = t3;
    }
    #undef DO_MM

    // ---- combine: logP = laccF + laccB + log(abar_512 . gamma_512) ----
    if (wv == 1) {
        float* CB = (float*)(SM + OFF_CMB);
        *(f32x4*)(CB + lr*CSTR +  0 + 4*g) = d0;
        *(f32x4*)(CB + lr*CSTR + 16 + 4*g) = d1;
        *(f32x4*)(CB + lr*CSTR + 32 + 4*g) = d2;
        *(f32x4*)(CB + lr*CSTR + 48 + 4*g) = d3;
        if (lane < 16) ((float*)(SM + OFF_LACB))[lane] = lacc;
    }
    __syncthreads();
    if (wv == 0) {
        const float* CB = (const float*)(SM + OFF_CMB);
        const f32x4 q0 = *(const f32x4*)(CB + lr*CSTR +  0 + 4*g);
        const f32x4 q1 = *(const f32x4*)(CB + lr*CSTR + 16 + 4*g);
        const f32x4 q2 = *(const f32x4*)(CB + lr*CSTR + 32 + 4*g);
        const f32x4 q3 = *(const f32x4*)(CB + lr*CSTR + 48 + 4*g);
        float dot = d0.x*q0.x + d0.y*q0.y + d0.z*q0.z + d0.w*q0.w
                  + d1.x*q1.x + d1.y*q1.y + d1.z*q1.z + d1.w*q1.w
                  + d2.x*q2.x + d2.y*q2.y + d2.z*q2.z + d2.w*q2.w
                  + d3.x*q3.x + d3.y*q3.y + d3.z*q3.z + d3.w*q3.w;
        dot += __shfl_xor(dot, 16);
        dot += __shfl_xor(dot, 32);
        float lp = lacc + ((const float*)(SM + OFF_LACB))[lr] + __logf(dot);
        if (g == 0) {                      // lanes 0..15: reduce over batch
            lp += __shfl_xor(lp, 1);
            lp += __shfl_xor(lp, 2);
            lp += __shfl_xor(lp, 4);
            lp += __shfl_xor(lp, 8);
            if (lr == 0) atomicAdd(out, lp * (1.0f / BATCH));
        }
    }
}

// ---------------------------------------------------------------------------
extern "C" void kernel_launch(void* const* d_in, const int* in_sizes, int n_in,
                              void* d_out, int out_size, void* d_ws, size_t ws_size,
                              hipStream_t stream) {
    const int*   y  = (const int*)  d_in[0];
    const float* T  = (const float*)d_in[1];
    const float* E  = (const float*)d_in[2];
    const float* Pi = (const float*)d_in[3];
    float* out = (float*)d_out;
    (void)d_ws; (void)ws_size; (void)in_sizes; (void)n_in; (void)out_size;

    hipMemsetAsync(out, 0, sizeof(float), stream);
    hipLaunchKernelGGL(hmm_fb, dim3(BATCH/16), dim3(128), 0, stream,
                       y, T, E, Pi, out);
}